// Round 2
// baseline (839.038 us; speedup 1.0000x reference)
//
#include <hip/hip_runtime.h>
#include <cstdint>

#define K_IN   4096
#define N_OUT  4096
#define M_ROWS 16384
#define RANK   8
#define LSCALE 1.0f   // alpha/rank = 8/8

typedef __attribute__((ext_vector_type(8))) short  short8;
typedef __attribute__((ext_vector_type(4))) float  floatx4;

// float -> bf16 bits, round-to-nearest-even
__device__ __forceinline__ unsigned short f2bf(float f) {
  uint32_t u = __float_as_uint(f);
  u += 0x7FFFu + ((u >> 16) & 1u);
  return (unsigned short)(u >> 16);
}

// W_eff[o][k] = W[o][k] + scale * sum_r B[o][r]*A[r][k], stored bf16
__global__ __launch_bounds__(256) void fold_w_kernel(
    const float* __restrict__ W, const float* __restrict__ lA,
    const float* __restrict__ lB, unsigned short* __restrict__ Weff) {
  int idx = blockIdx.x * 256 + threadIdx.x;   // one thread per 4 elems along k
  int o = idx >> 10;
  int k = (idx & 1023) << 2;
  float4 w = *reinterpret_cast<const float4*>(W + (size_t)o * K_IN + k);
#pragma unroll
  for (int r = 0; r < RANK; ++r) {
    float s = LSCALE * lB[o * RANK + r];
    float4 a = *reinterpret_cast<const float4*>(lA + r * K_IN + k);
    w.x += s * a.x; w.y += s * a.y; w.z += s * a.z; w.w += s * a.w;
  }
  ushort4 p;
  p.x = f2bf(w.x); p.y = f2bf(w.y); p.z = f2bf(w.z); p.w = f2bf(w.w);
  *reinterpret_cast<ushort4*>(Weff + (size_t)o * K_IN + k) = p;
}

__global__ __launch_bounds__(256) void cvt_x_kernel(
    const float* __restrict__ x, unsigned short* __restrict__ xb) {
  size_t i = ((size_t)blockIdx.x * 256 + threadIdx.x) * 8;
  float4 a = *reinterpret_cast<const float4*>(x + i);
  float4 c = *reinterpret_cast<const float4*>(x + i + 4);
  uint4 v;
  v.x = (uint32_t)f2bf(a.x) | ((uint32_t)f2bf(a.y) << 16);
  v.y = (uint32_t)f2bf(a.z) | ((uint32_t)f2bf(a.w) << 16);
  v.z = (uint32_t)f2bf(c.x) | ((uint32_t)f2bf(c.y) << 16);
  v.w = (uint32_t)f2bf(c.z) | ((uint32_t)f2bf(c.w) << 16);
  *reinterpret_cast<uint4*>(xb + i) = v;
}

__device__ __forceinline__ void gload_lds16(const void* g, void* l) {
  __builtin_amdgcn_global_load_lds(
      (const __attribute__((address_space(1))) void*)g,
      (__attribute__((address_space(3))) void*)l, 16, 0, 0);
}

#define BM 128
#define BN 128
#define BK 32

// C = Xb @ Weff^T + bias ; both inputs row-major, K contiguous (m97 structure)
__global__ __launch_bounds__(256) void gemm_kernel(
    const unsigned short* __restrict__ Xb, const unsigned short* __restrict__ Wb,
    const float* __restrict__ bias, float* __restrict__ out) {
  __shared__ unsigned short At[BM * BK];  // 8 KB
  __shared__ unsigned short Bt[BN * BK];  // 8 KB
  const int tid = threadIdx.x;
  const int wave = tid >> 6, lane = tid & 63;
  const int wr = wave >> 1, wc = wave & 1;       // 2x2 wave grid, 64x64 each
  const int l15 = lane & 15, lk = (lane >> 4) << 3;

  // XCD-aware swizzle: 4096 blocks, 8 XCDs, contiguous chunk per XCD
  int bx = blockIdx.x;
  int sbx = (bx & 7) * 512 + (bx >> 3);
  const int mt = sbx >> 5;    // 0..127
  const int nt = sbx & 31;    // 0..31

  const unsigned short* Asrc = Xb + (size_t)mt * BM * K_IN;
  const unsigned short* Bsrc = Wb + (size_t)nt * BN * K_IN;

  floatx4 acc[4][4];
#pragma unroll
  for (int i = 0; i < 4; ++i)
#pragma unroll
    for (int j = 0; j < 4; ++j)
      acc[i][j] = (floatx4){0.f, 0.f, 0.f, 0.f};

  for (int k0 = 0; k0 < K_IN; k0 += BK) {
    // stage 128x32 bf16 A and B tiles: 2 chunks x 16B per thread each
#pragma unroll
    for (int q = 0; q < 2; ++q) {
      int flat = (q * 256 + tid) * 8;      // bf16 element index in tile
      int row = flat >> 5, col = flat & 31;
      gload_lds16(Asrc + (size_t)row * K_IN + k0 + col,
                  (char*)At + q * 4096 + wave * 1024);
      gload_lds16(Bsrc + (size_t)row * K_IN + k0 + col,
                  (char*)Bt + q * 4096 + wave * 1024);
    }
    asm volatile("s_waitcnt vmcnt(0)" ::: "memory");
    __syncthreads();

    short8 af[4], bf[4];
#pragma unroll
    for (int i = 0; i < 4; ++i) {
      af[i] = *reinterpret_cast<const short8*>(&At[(wr * 64 + i * 16 + l15) * BK + lk]);
      bf[i] = *reinterpret_cast<const short8*>(&Bt[(wc * 64 + i * 16 + l15) * BK + lk]);
    }
#pragma unroll
    for (int i = 0; i < 4; ++i)
#pragma unroll
      for (int j = 0; j < 4; ++j)
        acc[i][j] = __builtin_amdgcn_mfma_f32_16x16x32_bf16(af[i], bf[j], acc[i][j], 0, 0, 0);
    __syncthreads();
  }

  // C/D layout: col = lane&15, row = (lane>>4)*4 + reg  (m89/m91 verified)
  const int row0 = mt * BM + wr * 64 + ((lane >> 4) << 2);
  const int col0 = nt * BN + wc * 64 + l15;
#pragma unroll
  for (int j = 0; j < 4; ++j) {
    int col = col0 + j * 16;
    float bv = bias[col];
#pragma unroll
    for (int i = 0; i < 4; ++i) {
      int row = row0 + i * 16;
#pragma unroll
      for (int r = 0; r < 4; ++r)
        out[(size_t)(row + r) * N_OUT + col] = acc[i][j][r] + bv;
    }
  }
}

// self-contained correct fallback (only if ws too small): tiled fp32
__global__ __launch_bounds__(256) void fallback_kernel(
    const float* __restrict__ x, const float* __restrict__ W,
    const float* __restrict__ bias, const float* __restrict__ lA,
    const float* __restrict__ lB, float* __restrict__ out) {
  __shared__ float Xs[64][17];
  __shared__ float Ws[64][17];
  int tid = threadIdx.x;
  int tx = tid & 15, ty = tid >> 4;
  int bm = blockIdx.y * 64, bn = blockIdx.x * 64;
  float acc[4][4] = {};
  for (int k0 = 0; k0 < K_IN; k0 += 16) {
#pragma unroll
    for (int q = 0; q < 4; ++q) {
      int flat = q * 256 + tid;
      int r = flat >> 4, c = flat & 15;
      Xs[r][c] = x[(size_t)(bm + r) * K_IN + k0 + c];
      float w = W[(size_t)(bn + r) * K_IN + k0 + c];
#pragma unroll
      for (int rr = 0; rr < RANK; ++rr)
        w += LSCALE * lB[(bn + r) * RANK + rr] * lA[rr * K_IN + k0 + c];
      Ws[r][c] = w;
    }
    __syncthreads();
#pragma unroll
    for (int kk = 0; kk < 16; ++kk) {
      float av[4], bv[4];
#pragma unroll
      for (int i = 0; i < 4; ++i) av[i] = Xs[ty * 4 + i][kk];
#pragma unroll
      for (int j = 0; j < 4; ++j) bv[j] = Ws[tx * 4 + j][kk];
#pragma unroll
      for (int i = 0; i < 4; ++i)
#pragma unroll
        for (int j = 0; j < 4; ++j) acc[i][j] += av[i] * bv[j];
    }
    __syncthreads();
  }
#pragma unroll
  for (int i = 0; i < 4; ++i)
#pragma unroll
    for (int j = 0; j < 4; ++j)
      out[(size_t)(bm + ty * 4 + i) * N_OUT + bn + tx * 4 + j] =
          acc[i][j] + bias[bn + tx * 4 + j];
}

extern "C" void kernel_launch(void* const* d_in, const int* in_sizes, int n_in,
                              void* d_out, int out_size, void* d_ws, size_t ws_size,
                              hipStream_t stream) {
  const float* x  = (const float*)d_in[0];
  const float* W  = (const float*)d_in[1];
  const float* b  = (const float*)d_in[2];
  const float* lA = (const float*)d_in[3];
  const float* lB = (const float*)d_in[4];
  float* out = (float*)d_out;

  const size_t weff_bytes = (size_t)N_OUT * K_IN * 2;    // 32 MB
  const size_t xb_bytes   = (size_t)M_ROWS * K_IN * 2;   // 128 MB

  if (ws_size >= weff_bytes + xb_bytes) {
    unsigned short* Weff = (unsigned short*)d_ws;
    unsigned short* Xb   = (unsigned short*)((char*)d_ws + weff_bytes);
    // N*K/4 elements-per-4 / 256 threads = 16384 blocks (round-1 fix: was 4096,
    // leaving 3/4 of Weff as poison -> out==bias there, absmax 5.65)
    fold_w_kernel<<<(int)(((size_t)N_OUT * K_IN / 4) / 256), 256, 0, stream>>>(W, lA, lB, Weff);
    cvt_x_kernel<<<(int)(((size_t)M_ROWS * K_IN / 8) / 256), 256, 0, stream>>>(x, Xb);
    gemm_kernel<<<(M_ROWS / BM) * (N_OUT / BN), 256, 0, stream>>>(Xb, Weff, b, out);
  } else {
    dim3 grid(N_OUT / 64, M_ROWS / 64);
    fallback_kernel<<<grid, 256, 0, stream>>>(x, W, b, lA, lB, out);
  }
}

// Round 4
// 711.650 us; speedup vs baseline: 1.1790x; 1.1790x over previous
//
#include <hip/hip_runtime.h>
#include <cstdint>

#define K_IN   4096
#define N_OUT  4096
#define M_ROWS 16384
#define RANK   8
#define LSCALE 1.0f   // alpha/rank = 8/8
#define NTILES 128    // K_IN / 32

typedef __attribute__((ext_vector_type(8))) short  short8;
typedef __attribute__((ext_vector_type(4))) float  floatx4;

// float -> bf16 bits, round-to-nearest-even
__device__ __forceinline__ unsigned short f2bf(float f) {
  uint32_t u = __float_as_uint(f);
  u += 0x7FFFu + ((u >> 16) & 1u);
  return (unsigned short)(u >> 16);
}

// W_eff[o][k] = W[o][k] + scale * sum_r B[o][r]*A[r][k], stored bf16
__global__ __launch_bounds__(256) void fold_w_kernel(
    const float* __restrict__ W, const float* __restrict__ lA,
    const float* __restrict__ lB, unsigned short* __restrict__ Weff) {
  int idx = blockIdx.x * 256 + threadIdx.x;
  int o = idx >> 10;
  int k = (idx & 1023) << 2;
  float4 w = *reinterpret_cast<const float4*>(W + (size_t)o * K_IN + k);
#pragma unroll
  for (int r = 0; r < RANK; ++r) {
    float s = LSCALE * lB[o * RANK + r];
    float4 a = *reinterpret_cast<const float4*>(lA + r * K_IN + k);
    w.x += s * a.x; w.y += s * a.y; w.z += s * a.z; w.w += s * a.w;
  }
  ushort4 p;
  p.x = f2bf(w.x); p.y = f2bf(w.y); p.z = f2bf(w.z); p.w = f2bf(w.w);
  *reinterpret_cast<ushort4*>(Weff + (size_t)o * K_IN + k) = p;
}

__global__ __launch_bounds__(256) void cvt_x_kernel(
    const float* __restrict__ x, unsigned short* __restrict__ xb) {
  size_t i = ((size_t)blockIdx.x * 256 + threadIdx.x) * 8;
  float4 a = *reinterpret_cast<const float4*>(x + i);
  float4 c = *reinterpret_cast<const float4*>(x + i + 4);
  uint4 v;
  v.x = (uint32_t)f2bf(a.x) | ((uint32_t)f2bf(a.y) << 16);
  v.y = (uint32_t)f2bf(a.z) | ((uint32_t)f2bf(a.w) << 16);
  v.z = (uint32_t)f2bf(c.x) | ((uint32_t)f2bf(c.y) << 16);
  v.w = (uint32_t)f2bf(c.z) | ((uint32_t)f2bf(c.w) << 16);
  *reinterpret_cast<uint4*>(xb + i) = v;
}

__device__ __forceinline__ void gload_lds16(const void* g, void* l) {
  __builtin_amdgcn_global_load_lds(
      (const __attribute__((address_space(1))) void*)g,
      (__attribute__((address_space(3))) void*)l, 16, 0, 0);
}

// ---------------------------------------------------------------------------
// 256x256 tile, BK=32, 512 threads (8 waves: 2M x 4N), ring-4 LDS pipeline.
// LDS per ring slot (32 KB): A tile 256x32 bf16 (16 KB) then B tile.
// Swizzle: element (row r, 16B-slot s) at LDS byte
//   L(r,s) = ((r<<6) | (s<<4)) ^ ((r&7)<<4)      (bijective XOR, 8 bank-groups)
// global_load_lds writes LDS linearly (base + lane*16), so the *source*
// address is pre-swizzled (rule 21: linear dest + inverse-swz source + swz read).
// Pipeline ledger (4 loads/wave/tile):
//   at wait of iter t, outstanding = tiles t..min(t+2,127).
//   required: tile t landed  =>  allowed leftover = 4*min(2, 127-t)
//   t<=125 -> vmcnt(8);  t==126 -> vmcnt(4);  t==127 -> vmcnt(0).
// (Round-3 bug: flat vmcnt(8) let t=126,127 read before their DMA landed —
//  passed cold first launch, failed warm graph replays. Drain fixed.)
// ---------------------------------------------------------------------------
__global__ __launch_bounds__(512, 2) void gemm_kernel(
    const unsigned short* __restrict__ Xb, const unsigned short* __restrict__ Wb,
    const float* __restrict__ bias, float* __restrict__ out) {
  __shared__ alignas(16) char lds[4 * 32768];   // 128 KiB, 1 block/CU

  const int tid  = threadIdx.x;
  const int wave = tid >> 6, lane = tid & 63;
  const int wr = wave >> 2, wc = wave & 3;      // 2 (M) x 4 (N) wave grid
  const int l15 = lane & 15, sq = lane >> 4;

  // XCD swizzle: 1024 blocks (%8==0 -> simple form valid), 128/XCD chunk
  int bx  = blockIdx.x;
  int sbx = (bx & 7) * 128 + (bx >> 3);
  const int mt = sbx >> 4;   // 0..63
  const int nt = sbx & 15;   // 0..15

  // Staging precompute: linear LDS byte L -> logical (r, s):
  //   r = (L>>7)*2 | ((L>>6 ^ L>>8)&1),  s = ((L>>4)&3) ^ (r&3)
  const unsigned short *gA0, *gA1, *gB0, *gB1;
  {
    int L0 = (wave * 2 + 0) * 1024 + lane * 16;
    int r0 = ((L0 >> 7) << 1) | (((L0 >> 6) ^ (L0 >> 8)) & 1);
    int s0 = ((L0 >> 4) & 3) ^ (r0 & 3);
    gA0 = Xb + (size_t)(mt * 256 + r0) * K_IN + s0 * 8;
    gB0 = Wb + (size_t)(nt * 256 + r0) * K_IN + s0 * 8;
    int L1 = (wave * 2 + 1) * 1024 + lane * 16;
    int r1 = ((L1 >> 7) << 1) | (((L1 >> 6) ^ (L1 >> 8)) & 1);
    int s1 = ((L1 >> 4) & 3) ^ (r1 & 3);
    gA1 = Xb + (size_t)(mt * 256 + r1) * K_IN + s1 * 8;
    gB1 = Wb + (size_t)(nt * 256 + r1) * K_IN + s1 * 8;
  }
  const int lo0 = (wave * 2 + 0) * 1024;
  const int lo1 = (wave * 2 + 1) * 1024;

#define STAGE(tt) do {                                        \
    char* base_ = lds + ((tt) & 3) * 32768;                   \
    gload_lds16(gA0 + (tt) * 32, base_ + lo0);                \
    gload_lds16(gB0 + (tt) * 32, base_ + 16384 + lo0);        \
    gload_lds16(gA1 + (tt) * 32, base_ + lo1);                \
    gload_lds16(gB1 + (tt) * 32, base_ + 16384 + lo1);        \
  } while (0)

  floatx4 acc[8][4];
#pragma unroll
  for (int i = 0; i < 8; ++i)
#pragma unroll
    for (int j = 0; j < 4; ++j)
      acc[i][j] = (floatx4){0.f, 0.f, 0.f, 0.f};

  // prologue: 3 tiles in flight, no wait
  STAGE(0); STAGE(1); STAGE(2);

  const int xorv = (l15 & 7) << 4;

  for (int t = 0; t < NTILES; ++t) {
    // drain schedule: tile t must be landed before the barrier releases reads
    if (t < NTILES - 2)       asm volatile("s_waitcnt vmcnt(8)" ::: "memory");
    else if (t == NTILES - 2) asm volatile("s_waitcnt vmcnt(4)" ::: "memory");
    else                      asm volatile("s_waitcnt vmcnt(0)" ::: "memory");
    __builtin_amdgcn_s_barrier();
    asm volatile("" ::: "memory");

    const char* Ab = lds + (t & 3) * 32768;
    const char* Bb = Ab + 16384;
    short8 af[8], bf[4];
#pragma unroll
    for (int i = 0; i < 8; ++i) {
      int rA = wr * 128 + i * 16 + l15;
      int LA = ((rA << 6) | (sq << 4)) ^ xorv;
      af[i] = *reinterpret_cast<const short8*>(Ab + LA);
    }
#pragma unroll
    for (int j = 0; j < 4; ++j) {
      int rB = wc * 64 + j * 16 + l15;
      int LB = ((rB << 6) | (sq << 4)) ^ xorv;
      bf[j] = *reinterpret_cast<const short8*>(Bb + LB);
    }
    // reads done before overwrite of ring slot (t+3)&3 == (t-1)&3
    asm volatile("s_waitcnt lgkmcnt(0)" ::: "memory");
    __builtin_amdgcn_s_barrier();
    asm volatile("" ::: "memory");

    if (t + 3 < NTILES) STAGE(t + 3);

#pragma unroll
    for (int i = 0; i < 8; ++i)
#pragma unroll
      for (int j = 0; j < 4; ++j)
        acc[i][j] = __builtin_amdgcn_mfma_f32_16x16x32_bf16(af[i], bf[j], acc[i][j], 0, 0, 0);
  }
#undef STAGE

  // epilogue: C/D layout col=lane&15, row=(lane>>4)*4+reg (m89/m91 verified)
  const int row0 = mt * 256 + wr * 128 + sq * 4;
  const int col0 = nt * 256 + wc * 64 + l15;
#pragma unroll
  for (int j = 0; j < 4; ++j) {
    int col = col0 + j * 16;
    float bv = bias[col];
#pragma unroll
    for (int i = 0; i < 8; ++i) {
      int rowb = row0 + i * 16;
#pragma unroll
      for (int rr = 0; rr < 4; ++rr)
        out[(size_t)(rowb + rr) * N_OUT + col] = acc[i][j][rr] + bv;
    }
  }
}

// self-contained correct fallback (only if ws too small): tiled fp32
__global__ __launch_bounds__(256) void fallback_kernel(
    const float* __restrict__ x, const float* __restrict__ W,
    const float* __restrict__ bias, const float* __restrict__ lA,
    const float* __restrict__ lB, float* __restrict__ out) {
  __shared__ float Xs[64][17];
  __shared__ float Ws[64][17];
  int tid = threadIdx.x;
  int tx = tid & 15, ty = tid >> 4;
  int bm = blockIdx.y * 64, bn = blockIdx.x * 64;
  float acc[4][4] = {};
  for (int k0 = 0; k0 < K_IN; k0 += 16) {
#pragma unroll
    for (int q = 0; q < 4; ++q) {
      int flat = q * 256 + tid;
      int r = flat >> 4, c = flat & 15;
      Xs[r][c] = x[(size_t)(bm + r) * K_IN + k0 + c];
      float w = W[(size_t)(bn + r) * K_IN + k0 + c];
#pragma unroll
      for (int rr = 0; rr < RANK; ++rr)
        w += LSCALE * lB[(bn + r) * RANK + rr] * lA[rr * K_IN + k0 + c];
      Ws[r][c] = w;
    }
    __syncthreads();
#pragma unroll
    for (int kk = 0; kk < 16; ++kk) {
      float av[4], bv[4];
#pragma unroll
      for (int i = 0; i < 4; ++i) av[i] = Xs[ty * 4 + i][kk];
#pragma unroll
      for (int j = 0; j < 4; ++j) bv[j] = Ws[tx * 4 + j][kk];
#pragma unroll
      for (int i = 0; i < 4; ++i)
#pragma unroll
        for (int j = 0; j < 4; ++j) acc[i][j] += av[i] * bv[j];
    }
    __syncthreads();
  }
#pragma unroll
  for (int i = 0; i < 4; ++i)
#pragma unroll
    for (int j = 0; j < 4; ++j)
      out[(size_t)(bm + ty * 4 + i) * N_OUT + bn + tx * 4 + j] =
          acc[i][j] + bias[bn + tx * 4 + j];
}

extern "C" void kernel_launch(void* const* d_in, const int* in_sizes, int n_in,
                              void* d_out, int out_size, void* d_ws, size_t ws_size,
                              hipStream_t stream) {
  const float* x  = (const float*)d_in[0];
  const float* W  = (const float*)d_in[1];
  const float* b  = (const float*)d_in[2];
  const float* lA = (const float*)d_in[3];
  const float* lB = (const float*)d_in[4];
  float* out = (float*)d_out;

  const size_t weff_bytes = (size_t)N_OUT * K_IN * 2;    // 32 MB
  const size_t xb_bytes   = (size_t)M_ROWS * K_IN * 2;   // 128 MB

  if (ws_size >= weff_bytes + xb_bytes) {
    unsigned short* Weff = (unsigned short*)d_ws;
    unsigned short* Xb   = (unsigned short*)((char*)d_ws + weff_bytes);
    fold_w_kernel<<<(int)(((size_t)N_OUT * K_IN / 4) / 256), 256, 0, stream>>>(W, lA, lB, Weff);
    cvt_x_kernel<<<(int)(((size_t)M_ROWS * K_IN / 8) / 256), 256, 0, stream>>>(x, Xb);
    gemm_kernel<<<(M_ROWS / 256) * (N_OUT / 256), 512, 0, stream>>>(Xb, Weff, b, out);
  } else {
    dim3 grid(N_OUT / 64, M_ROWS / 64);
    fallback_kernel<<<grid, 256, 0, stream>>>(x, W, b, lA, lB, out);
  }
}

// Round 5
// 638.947 us; speedup vs baseline: 1.3132x; 1.1138x over previous
//
#include <hip/hip_runtime.h>
#include <cstdint>

#define K_IN   4096
#define N_OUT  4096
#define M_ROWS 16384
#define RANK   8
#define LSCALE 1.0f   // alpha/rank = 8/8
#define NT     64     // K_IN / 64  (BK=64 K-tiles)

typedef __attribute__((ext_vector_type(8))) short  short8;
typedef __attribute__((ext_vector_type(4))) float  floatx4;

__device__ __forceinline__ unsigned short f2bf(float f) {
  uint32_t u = __float_as_uint(f);
  u += 0x7FFFu + ((u >> 16) & 1u);
  return (unsigned short)(u >> 16);
}

__global__ __launch_bounds__(256) void fold_w_kernel(
    const float* __restrict__ W, const float* __restrict__ lA,
    const float* __restrict__ lB, unsigned short* __restrict__ Weff) {
  int idx = blockIdx.x * 256 + threadIdx.x;
  int o = idx >> 10;
  int k = (idx & 1023) << 2;
  float4 w = *reinterpret_cast<const float4*>(W + (size_t)o * K_IN + k);
#pragma unroll
  for (int r = 0; r < RANK; ++r) {
    float s = LSCALE * lB[o * RANK + r];
    float4 a = *reinterpret_cast<const float4*>(lA + r * K_IN + k);
    w.x += s * a.x; w.y += s * a.y; w.z += s * a.z; w.w += s * a.w;
  }
  ushort4 p;
  p.x = f2bf(w.x); p.y = f2bf(w.y); p.z = f2bf(w.z); p.w = f2bf(w.w);
  *reinterpret_cast<ushort4*>(Weff + (size_t)o * K_IN + k) = p;
}

__global__ __launch_bounds__(256) void cvt_x_kernel(
    const float* __restrict__ x, unsigned short* __restrict__ xb) {
  size_t i = ((size_t)blockIdx.x * 256 + threadIdx.x) * 8;
  float4 a = *reinterpret_cast<const float4*>(x + i);
  float4 c = *reinterpret_cast<const float4*>(x + i + 4);
  uint4 v;
  v.x = (uint32_t)f2bf(a.x) | ((uint32_t)f2bf(a.y) << 16);
  v.y = (uint32_t)f2bf(a.z) | ((uint32_t)f2bf(a.w) << 16);
  v.z = (uint32_t)f2bf(c.x) | ((uint32_t)f2bf(c.y) << 16);
  v.w = (uint32_t)f2bf(c.z) | ((uint32_t)f2bf(c.w) << 16);
  *reinterpret_cast<uint4*>(xb + i) = v;
}

__device__ __forceinline__ void gload_lds16(const void* g, void* l) {
  __builtin_amdgcn_global_load_lds(
      (const __attribute__((address_space(1))) void*)g,
      (__attribute__((address_space(3))) void*)l, 16, 0, 0);
}

// ---------------------------------------------------------------------------
// 256x256 tile, BK=64, 512 threads (8 waves: 2M x 4N), 8-phase schedule
// (T2 swizzle + T3 phases + T4 counted vmcnt + T5 setprio), double-buffered.
// Per K-tile buffer (64KB): Ak0 | Ak1 | Bk0 | Bk1, each 256 rows x 32 K bf16
// (16KB, 64B rows). Swizzle within a half: L(r,s)=((r<<6)|(s<<4))^((r&7)<<4)
// (HW-validated rounds 2-4); global_load_lds dest linear, source pre-swizzled.
// Phases per K-tile t: P(mh,ks) = (0,0),(1,0),(0,1),(1,1):
//   ds-read 4 A-frags (+4 B-frags when entering a new ks) | stage one half of
//   t+1 | barrier | lgkmcnt(0) | setprio(1) 16xMFMA setprio(0) | barrier.
// vmcnt ledger (in-order, oldest-first; 2 loads per half per thread):
//   P1-end: outstanding = {Ak1,Bk1}(t), {Ak0,Bk0}(t+1) = 8 -> vmcnt(4)
//           retires exactly {Ak1,Bk1}(t) before P2 reads them.
//   P3-end: outstanding = 4 halves of t+1 = 8 -> vmcnt(4) retires
//           {Ak0,Bk0}(t+1) before next P0.  Waits precede a barrier so all
//           waves' DMA is certified for all readers.  Tail t=63: P1-end
//           vmcnt(0) (only 4 outstanding), P3-end skip.  Never 0 mid-loop.
// ---------------------------------------------------------------------------
__global__ __launch_bounds__(512, 2) void gemm_kernel(
    const unsigned short* __restrict__ Xb, const unsigned short* __restrict__ Wb,
    const float* __restrict__ bias, float* __restrict__ out) {
  __shared__ alignas(16) char lds[2 * 65536];   // 128 KiB

  const int tid  = threadIdx.x;
  const int wave = tid >> 6, lane = tid & 63;
  const int wr = wave >> 2, wc = wave & 3;      // 2 (M) x 4 (N) wave grid
  const int l15 = lane & 15, sq = lane >> 4;
  const int xorv = (l15 & 7) << 4;

  // XCD swizzle: 1024 blocks (%8==0), contiguous 128-tile chunk per XCD
  int bx  = blockIdx.x;
  int sbx = (bx & 7) * 128 + (bx >> 3);
  const int mt = sbx >> 4;   // 0..63
  const int nt = sbx & 15;   // 0..15

  // staging source pre-swizzle: linear LDS byte L -> logical (r,s):
  //   r = (L>>7)*2 | ((L>>6 ^ L>>8)&1),  s = ((L>>4)&3) ^ (r&3)
  const unsigned short *gA0, *gA1, *gB0, *gB1;
  {
    int L0 = tid * 16;
    int r0 = ((L0 >> 7) << 1) | (((L0 >> 6) ^ (L0 >> 8)) & 1);
    int s0 = ((L0 >> 4) & 3) ^ (r0 & 3);
    gA0 = Xb + (size_t)(mt * 256 + r0) * K_IN + s0 * 8;
    gB0 = Wb + (size_t)(nt * 256 + r0) * K_IN + s0 * 8;
    int L1 = 8192 + tid * 16;
    int r1 = ((L1 >> 7) << 1) | (((L1 >> 6) ^ (L1 >> 8)) & 1);
    int s1 = ((L1 >> 4) & 3) ^ (r1 & 3);
    gA1 = Xb + (size_t)(mt * 256 + r1) * K_IN + s1 * 8;
    gB1 = Wb + (size_t)(nt * 256 + r1) * K_IN + s1 * 8;
  }

#define STAGE_A(TT, KS) do {                                         \
    char* d_ = lds + ((TT) & 1) * 65536 + (KS) * 16384 + tid * 16;   \
    gload_lds16(gA0 + (TT) * 64 + (KS) * 32, d_);                    \
    gload_lds16(gA1 + (TT) * 64 + (KS) * 32, d_ + 8192);             \
  } while (0)
#define STAGE_B(TT, KS) do {                                         \
    char* d_ = lds + ((TT) & 1) * 65536 + 32768 + (KS) * 16384 + tid * 16; \
    gload_lds16(gB0 + (TT) * 64 + (KS) * 32, d_);                    \
    gload_lds16(gB1 + (TT) * 64 + (KS) * 32, d_ + 8192);             \
  } while (0)
#define BAR() do { asm volatile("" ::: "memory");                    \
    __builtin_amdgcn_s_barrier();                                    \
    asm volatile("" ::: "memory"); } while (0)
#define LGKM0() asm volatile("s_waitcnt lgkmcnt(0)" ::: "memory")
#define LOAD_AF(MH, KS) do {                                         \
    const char* Ah_ = lds + tb + (KS) * 16384;                       \
    _Pragma("unroll")                                                \
    for (int i = 0; i < 4; ++i) {                                    \
      int rA_ = wr * 128 + ((MH) * 4 + i) * 16 + l15;                \
      int LA_ = ((rA_ << 6) | (sq << 4)) ^ xorv;                     \
      af[i] = *reinterpret_cast<const short8*>(Ah_ + LA_);           \
    } } while (0)
#define LOAD_BF(KS) do {                                             \
    const char* Bh_ = lds + tb + 32768 + (KS) * 16384;               \
    _Pragma("unroll")                                                \
    for (int j = 0; j < 4; ++j) {                                    \
      int rB_ = wc * 64 + j * 16 + l15;                              \
      int LB_ = ((rB_ << 6) | (sq << 4)) ^ xorv;                     \
      bf[j] = *reinterpret_cast<const short8*>(Bh_ + LB_);           \
    } } while (0)
#define DO_MFMA(MH) do {                                             \
    __builtin_amdgcn_s_setprio(1);                                   \
    _Pragma("unroll")                                                \
    for (int i = 0; i < 4; ++i)                                      \
      _Pragma("unroll")                                              \
      for (int j = 0; j < 4; ++j)                                    \
        acc[(MH) * 4 + i][j] = __builtin_amdgcn_mfma_f32_16x16x32_bf16( \
            af[i], bf[j], acc[(MH) * 4 + i][j], 0, 0, 0);            \
    __builtin_amdgcn_s_setprio(0); } while (0)

  floatx4 acc[8][4];
#pragma unroll
  for (int i = 0; i < 8; ++i)
#pragma unroll
    for (int j = 0; j < 4; ++j)
      acc[i][j] = (floatx4){0.f, 0.f, 0.f, 0.f};

  // prologue: stage all 4 halves of t=0 (issue order Ak0,Bk0,Ak1,Bk1),
  // then certify {Ak0,Bk0}(0) for everyone.
  STAGE_A(0, 0); STAGE_B(0, 0); STAGE_A(0, 1); STAGE_B(0, 1);
  asm volatile("s_waitcnt vmcnt(4)" ::: "memory");
  BAR();

  short8 af[4], bf[4];

  for (int t = 0; t < NT; ++t) {
    const int tb = (t & 1) * 65536;
    const bool more = (t + 1 < NT);

    // ---- P0: mh0/ks0; stage Ak0(t+1)
    LOAD_AF(0, 0);
    LOAD_BF(0);
    if (more) STAGE_A(t + 1, 0);
    BAR(); LGKM0();
    DO_MFMA(0);
    BAR();

    // ---- P1: mh1/ks0; stage Bk0(t+1); wait-2 certifies {Ak1,Bk1}(t)
    LOAD_AF(1, 0);
    if (more) STAGE_B(t + 1, 0);
    BAR(); LGKM0();
    DO_MFMA(1);
    if (more) asm volatile("s_waitcnt vmcnt(4)" ::: "memory");
    else      asm volatile("s_waitcnt vmcnt(0)" ::: "memory");
    BAR();

    // ---- P2: mh0/ks1; stage Ak1(t+1)
    LOAD_AF(0, 1);
    LOAD_BF(1);
    if (more) STAGE_A(t + 1, 1);
    BAR(); LGKM0();
    DO_MFMA(0);
    BAR();

    // ---- P3: mh1/ks1; stage Bk1(t+1); wait-1 certifies {Ak0,Bk0}(t+1)
    LOAD_AF(1, 1);
    if (more) STAGE_B(t + 1, 1);
    BAR(); LGKM0();
    DO_MFMA(1);
    if (more) asm volatile("s_waitcnt vmcnt(4)" ::: "memory");
    BAR();
  }
#undef STAGE_A
#undef STAGE_B
#undef LOAD_AF
#undef LOAD_BF
#undef DO_MFMA

  // epilogue: C/D layout col=lane&15, row=(lane>>4)*4+reg (m89/m91 verified)
  const int row0 = mt * 256 + wr * 128 + sq * 4;
  const int col0 = nt * 256 + wc * 64 + l15;
#pragma unroll
  for (int j = 0; j < 4; ++j) {
    int col = col0 + j * 16;
    float bv = bias[col];
#pragma unroll
    for (int i = 0; i < 8; ++i) {
      int rowb = row0 + i * 16;
#pragma unroll
      for (int rr = 0; rr < 4; ++rr)
        out[(size_t)(rowb + rr) * N_OUT + col] = acc[i][j][rr] + bv;
    }
  }
}

// self-contained correct fallback (only if ws too small): tiled fp32
__global__ __launch_bounds__(256) void fallback_kernel(
    const float* __restrict__ x, const float* __restrict__ W,
    const float* __restrict__ bias, const float* __restrict__ lA,
    const float* __restrict__ lB, float* __restrict__ out) {
  __shared__ float Xs[64][17];
  __shared__ float Ws[64][17];
  int tid = threadIdx.x;
  int tx = tid & 15, ty = tid >> 4;
  int bm = blockIdx.y * 64, bn = blockIdx.x * 64;
  float acc[4][4] = {};
  for (int k0 = 0; k0 < K_IN; k0 += 16) {
#pragma unroll
    for (int q = 0; q < 4; ++q) {
      int flat = q * 256 + tid;
      int r = flat >> 4, c = flat & 15;
      Xs[r][c] = x[(size_t)(bm + r) * K_IN + k0 + c];
      float w = W[(size_t)(bn + r) * K_IN + k0 + c];
#pragma unroll
      for (int rr = 0; rr < RANK; ++rr)
        w += LSCALE * lB[(bn + r) * RANK + rr] * lA[rr * K_IN + k0 + c];
      Ws[r][c] = w;
    }
    __syncthreads();
#pragma unroll
    for (int kk = 0; kk < 16; ++kk) {
      float av[4], bv[4];
#pragma unroll
      for (int i = 0; i < 4; ++i) av[i] = Xs[ty * 4 + i][kk];
#pragma unroll
      for (int j = 0; j < 4; ++j) bv[j] = Ws[tx * 4 + j][kk];
#pragma unroll
      for (int i = 0; i < 4; ++i)
#pragma unroll
        for (int j = 0; j < 4; ++j) acc[i][j] += av[i] * bv[j];
    }
    __syncthreads();
  }
#pragma unroll
  for (int i = 0; i < 4; ++i)
#pragma unroll
    for (int j = 0; j < 4; ++j)
      out[(size_t)(bm + ty * 4 + i) * N_OUT + bn + tx * 4 + j] =
          acc[i][j] + bias[bn + tx * 4 + j];
}

extern "C" void kernel_launch(void* const* d_in, const int* in_sizes, int n_in,
                              void* d_out, int out_size, void* d_ws, size_t ws_size,
                              hipStream_t stream) {
  const float* x  = (const float*)d_in[0];
  const float* W  = (const float*)d_in[1];
  const float* b  = (const float*)d_in[2];
  const float* lA = (const float*)d_in[3];
  const float* lB = (const float*)d_in[4];
  float* out = (float*)d_out;

  const size_t weff_bytes = (size_t)N_OUT * K_IN * 2;    // 32 MB
  const size_t xb_bytes   = (size_t)M_ROWS * K_IN * 2;   // 128 MB

  if (ws_size >= weff_bytes + xb_bytes) {
    unsigned short* Weff = (unsigned short*)d_ws;
    unsigned short* Xb   = (unsigned short*)((char*)d_ws + weff_bytes);
    fold_w_kernel<<<(int)(((size_t)N_OUT * K_IN / 4) / 256), 256, 0, stream>>>(W, lA, lB, Weff);
    cvt_x_kernel<<<(int)(((size_t)M_ROWS * K_IN / 8) / 256), 256, 0, stream>>>(x, Xb);
    gemm_kernel<<<(M_ROWS / 256) * (N_OUT / 256), 512, 0, stream>>>(Xb, Weff, b, out);
  } else {
    dim3 grid(N_OUT / 64, M_ROWS / 64);
    fallback_kernel<<<grid, 256, 0, stream>>>(x, W, b, lA, lB, out);
  }
}